// Round 1
// baseline (37.561 us; speedup 1.0000x reference)
//
#include <hip/hip_runtime.h>

#define HEIGHT 8

__global__ void __launch_bounds__(512)
roi_rotate_kernel(const float* __restrict__ images,
                  const float* __restrict__ boxes,
                  const int* __restrict__ box_indices,
                  float* __restrict__ crops,
                  float* __restrict__ width_out,
                  int max_width, int Himg, int Wimg)
{
    const int m   = blockIdx.x;
    const int tid = threadIdx.x;             // 0 .. HEIGHT*max_width-1
    const int i   = tid / max_width;
    const int j   = tid - i * max_width;

    __shared__ float p[6];  // cx, cy, s, width, ca, sa
    if (tid == 0) {
        float x1  = boxes[m * 5 + 0];
        float y1  = boxes[m * 5 + 1];
        float x2  = boxes[m * 5 + 2];
        float y2  = boxes[m * 5 + 3];
        float ang = boxes[m * 5 + 4];
        float bw = x2 - x1, bh = y2 - y1;
        float width = (float)HEIGHT * bw / bh;
        p[0] = (x1 + x2) * 0.5f;
        p[1] = (y1 + y2) * 0.5f;
        p[2] = bh / (float)HEIGHT;
        p[3] = width;
        p[4] = cosf(ang);
        p[5] = sinf(ang);
        width_out[m] = (float)max_width - width;
    }
    __syncthreads();
    const float cx = p[0], cy = p[1], s = p[2], width = p[3], ca = p[4], sa = p[5];

    const float dx = s * ((float)j - (width  - 1.0f) * 0.5f);
    const float dy = s * ((float)i - ((float)HEIGHT - 1.0f) * 0.5f);
    const float sx = cx + ca * dx - sa * dy;
    const float sy = cy + sa * dx + ca * dy;

    float* o = crops + ((size_t)(m * HEIGHT + i) * max_width + j) * 3;

    const bool valid = ((float)j < ceilf(width)) &&
                       (sx >= 0.0f) && (sx <= (float)(Wimg - 1)) &&
                       (sy >= 0.0f) && (sy <= (float)(Himg - 1));

    if (!valid) {
        o[0] = 0.0f; o[1] = 0.0f; o[2] = 0.0f;
        return;
    }

    const float x0 = floorf(sx);
    const float y0 = floorf(sy);
    const float fx = sx - x0;
    const float fy = sy - y0;
    const int x0i = (int)fminf(fmaxf(x0,        0.0f), (float)(Wimg - 1));
    const int x1i = (int)fminf(fmaxf(x0 + 1.0f, 0.0f), (float)(Wimg - 1));
    const int y0i = (int)fminf(fmaxf(y0,        0.0f), (float)(Himg - 1));
    const int y1i = (int)fminf(fmaxf(y0 + 1.0f, 0.0f), (float)(Himg - 1));

    const int b = box_indices[m];
    const float* img = images + (size_t)b * Himg * Wimg * 3;
    const size_t o00 = ((size_t)y0i * Wimg + x0i) * 3;
    const size_t o01 = ((size_t)y0i * Wimg + x1i) * 3;
    const size_t o10 = ((size_t)y1i * Wimg + x0i) * 3;
    const size_t o11 = ((size_t)y1i * Wimg + x1i) * 3;

    const float w00 = (1.0f - fx) * (1.0f - fy);
    const float w01 = fx * (1.0f - fy);
    const float w10 = (1.0f - fx) * fy;
    const float w11 = fx * fy;

    #pragma unroll
    for (int c = 0; c < 3; ++c) {
        float v = images ? 0.0f : 0.0f;
        v = img[o00 + c] * w00 + img[o01 + c] * w01 +
            img[o10 + c] * w10 + img[o11 + c] * w11;
        o[c] = v;
    }
}

extern "C" void kernel_launch(void* const* d_in, const int* in_sizes, int n_in,
                              void* d_out, int out_size, void* d_ws, size_t ws_size,
                              hipStream_t stream) {
    const float* images      = (const float*)d_in[0];
    const float* boxes       = (const float*)d_in[2];
    const int*   box_indices = (const int*)d_in[3];

    const int M  = in_sizes[3];                       // 8192 boxes
    const int mw = (out_size - M) / (M * HEIGHT * 3); // max_width (=64)
    const int Himg = 512, Wimg = 512;

    float* crops     = (float*)d_out;
    float* width_out = crops + (size_t)M * HEIGHT * mw * 3;

    dim3 block(HEIGHT * mw);   // 512 threads = one box
    dim3 grid(M);
    roi_rotate_kernel<<<grid, block, 0, stream>>>(images, boxes, box_indices,
                                                  crops, width_out, mw, Himg, Wimg);
}